// Round 7
// baseline (341.871 us; speedup 1.0000x reference)
//
#include <hip/hip_runtime.h>
#include <hip/hip_cooperative_groups.h>
#include <stdint.h>

namespace cg = cooperative_groups;

// Problem constants (from reference)
#define B_SZ   512
#define T_SZ   100
#define NPRE   256
#define NPOST  256
#define KTOT   (B_SZ * T_SZ)   // 51200

typedef __bf16 bf16x8 __attribute__((ext_vector_type(8)));
typedef float  floatx4 __attribute__((ext_vector_type(4)));

__device__ __forceinline__ uint32_t bf16_rne(float v) {
    uint32_t bits = __float_as_uint(v);
    return (bits + 0x7FFFu + ((bits >> 16) & 1u)) >> 16;
}
__device__ __forceinline__ uint32_t pack_trunc2(float a, float b) {
    return (__float_as_uint(a) >> 16) | (__float_as_uint(b) & 0xFFFF0000u);
}

// ---------------------------------------------------------------------------
// Cooperative mega-kernel: 256 blocks x 512 threads, all co-resident
// (64 KB LDS, ~110 VGPR -> 1 block/CU guaranteed).
//   Phase 1 (prep):   block bx computes traces for batches {2bx, 2bx+1}
//                     (two 256-thread groups, R4-proven scan+transpose),
//                     writes bf16 fragment lines to trace_t.
//   grid.sync()
//   Phase 2 (gemm):   s = bx&127 (batches 4s..4s+3), pt = bx>>7; tile
//                     128p x 256q; A = direct dwordx4 fragment-line loads,
//                     B = fp32 post staged to LDS bf16 lines (R6-proven).
//   grid.sync()
//   Phase 3 (reduce): 2 threads per output element, 64 splits each,
//                     shfl_xor combine, scale, store.
// ---------------------------------------------------------------------------
__global__ __launch_bounds__(512) void stdp_mega(
    const float* __restrict__ pre, const float* __restrict__ post,
    unsigned short* __restrict__ trace_t, float* __restrict__ partial,
    float* __restrict__ out)
{
    __shared__ __align__(16) unsigned char smem[65536];
    cg::grid_group grid = cg::this_grid();

    const int bx  = blockIdx.x;   // 0..255
    const int tid = threadIdx.x;  // 0..511

    // ===================== Phase 1: trace prep =====================
    {
        const int g = tid >> 8;           // batch-group 0/1
        const int p = tid & 255;          // pre-neuron
        const int lane = p & 63, wave = p >> 6;
        const int b = 2 * bx + g;
        unsigned short (*T_lds)[256][8] =
            (unsigned short (*)[256][8])(smem + g * 16384);  // [4][256][8]
        const float decay = 0.95122942450071400910f;  // expf(-1/20)
        const float* src = pre + (size_t)b * (T_SZ * NPRE) + p;

        float carry = 0.0f;
        for (int kc = 0; kc < 4; ++kc) {
            uint32_t pk[16];
            if (kc < 3) {
                float x[32];
#pragma unroll
                for (int j = 0; j < 32; ++j)
                    x[j] = src[(size_t)(kc * 32 + j) * NPRE];
#pragma unroll
                for (int j = 0; j < 16; ++j) {
                    uint32_t lo = bf16_rne(carry);   // trace[t]=carry, then update
                    carry = decay * (carry + x[2 * j]);
                    uint32_t hi = bf16_rne(carry);
                    carry = decay * (carry + x[2 * j + 1]);
                    pk[j] = lo | (hi << 16);
                }
            } else {
                float x[4];
#pragma unroll
                for (int j = 0; j < 4; ++j)
                    x[j] = src[(size_t)(96 + j) * NPRE];
#pragma unroll
                for (int j = 0; j < 2; ++j) {
                    uint32_t lo = bf16_rne(carry);
                    carry = decay * (carry + x[2 * j]);
                    uint32_t hi = bf16_rne(carry);
                    carry = decay * (carry + x[2 * j + 1]);
                    pk[j] = lo | (hi << 16);
                }
#pragma unroll
                for (int j = 2; j < 16; ++j) pk[j] = 0u;  // t >= 100 -> zero
            }
#pragma unroll
            for (int o = 0; o < 4; ++o)
                *(uint4*)&T_lds[o][p][0] =
                    make_uint4(pk[o * 4], pk[o * 4 + 1], pk[o * 4 + 2], pk[o * 4 + 3]);
            __syncthreads();
#pragma unroll
            for (int i = 0; i < 4; ++i) {
                int pg = wave * 4 + i;
                uint4 v = *(const uint4*)&T_lds[lane >> 4][pg * 16 + (lane & 15)][0];
                *(uint4*)(trace_t + (((size_t)(b * 4 + kc) * 16 + pg) << 9) + lane * 8) = v;
            }
            __syncthreads();
        }
    }

    __threadfence();
    grid.sync();

    // ===================== Phase 2: split-K MFMA GEMM =====================
    {
        unsigned short (*B_lds)[512] = (unsigned short (*)[512])smem;  // 64 KB

        const int s  = bx & 127;          // K-split (batches 4s..4s+3)
        const int pt = bx >> 7;           // p-tile
        const int lane = tid & 63, wave = tid >> 6;
        const int wp = wave & 3, wq = wave >> 2;
        const int l15 = lane & 15, l4 = lane >> 4;
        const int q = tid & 255, hh = tid >> 8;  // staging role (wave-uniform hh)
        const int qg = q >> 4, q15 = q & 15;

        floatx4 acc[2][8] = {};

        for (int lb = 0; lb < 4; ++lb) {
            const int b = s * 4 + lb;

            // ---- A prefetch (global fragment lines)
            bf16x8 a_pf[4][2];
#pragma unroll
            for (int kc = 0; kc < 4; ++kc)
#pragma unroll
                for (int f = 0; f < 2; ++f) {
                    int pg = pt * 8 + wp * 2 + f;
                    a_pf[kc][f] = *(const bf16x8*)(
                        trace_t + (((size_t)(b * 4 + kc) * 16 + pg) << 9) + lane * 8);
                }

            // ---- B staging: flat batched loads, no conditionals
            const float* pb = post + (size_t)b * (T_SZ * NPOST) + q;
            if (hh == 0) {
                // octs 0..7 (t 0..63)
#pragma unroll
                for (int half = 0; half < 2; ++half) {
                    float x[32];
#pragma unroll
                    for (int j = 0; j < 32; ++j)
                        x[j] = pb[(size_t)(half * 32 + j) * NPOST];
#pragma unroll
                    for (int o = 0; o < 4; ++o) {
                        int oct = half * 4 + o;
                        uint4 v = make_uint4(pack_trunc2(x[o * 8 + 0], x[o * 8 + 1]),
                                             pack_trunc2(x[o * 8 + 2], x[o * 8 + 3]),
                                             pack_trunc2(x[o * 8 + 4], x[o * 8 + 5]),
                                             pack_trunc2(x[o * 8 + 6], x[o * 8 + 7]));
                        *(uint4*)&B_lds[(oct >> 2) * 16 + qg][(((oct & 3) * 16 + q15)) * 8] = v;
                    }
                }
            } else {
                // octs 8..11 (t 64..95)
                float x[32];
#pragma unroll
                for (int j = 0; j < 32; ++j)
                    x[j] = pb[(size_t)(64 + j) * NPOST];
                float y[4];
#pragma unroll
                for (int j = 0; j < 4; ++j)
                    y[j] = pb[(size_t)(96 + j) * NPOST];
#pragma unroll
                for (int o = 0; o < 4; ++o) {
                    int oct = 8 + o;
                    uint4 v = make_uint4(pack_trunc2(x[o * 8 + 0], x[o * 8 + 1]),
                                         pack_trunc2(x[o * 8 + 2], x[o * 8 + 3]),
                                         pack_trunc2(x[o * 8 + 4], x[o * 8 + 5]),
                                         pack_trunc2(x[o * 8 + 6], x[o * 8 + 7]));
                    *(uint4*)&B_lds[(oct >> 2) * 16 + qg][(((oct & 3) * 16 + q15)) * 8] = v;
                }
                // oct 12: t 96..99 real, 100..103 zero
                *(uint4*)&B_lds[3 * 16 + qg][(q15) * 8] =
                    make_uint4(pack_trunc2(y[0], y[1]), pack_trunc2(y[2], y[3]), 0u, 0u);
                // octs 13..15: zero
#pragma unroll
                for (int o = 13; o < 16; ++o)
                    *(uint4*)&B_lds[3 * 16 + qg][(((o & 3) * 16 + q15)) * 8] =
                        make_uint4(0u, 0u, 0u, 0u);
            }
            __syncthreads();

            // ---- MFMA: 4 chunks of K=32
#pragma unroll
            for (int kc = 0; kc < 4; ++kc) {
                bf16x8 bb[8];
#pragma unroll
                for (int gg = 0; gg < 8; ++gg)
                    bb[gg] = *(const bf16x8*)&B_lds[kc * 16 + wq * 8 + gg][lane * 8];
#pragma unroll
                for (int f = 0; f < 2; ++f)
#pragma unroll
                    for (int gg = 0; gg < 8; ++gg)
                        acc[f][gg] = __builtin_amdgcn_mfma_f32_16x16x32_bf16(
                            a_pf[kc][f], bb[gg], acc[f][gg], 0, 0, 0);
            }
            __syncthreads();
        }

        // ---- writeout: partial[bx][p_loc 128][q 256]
        // C/D layout (m89/m91): col = lane&15, row = (lane>>4)*4 + reg
        float* pout = partial + (size_t)bx * (128 * 256);
#pragma unroll
        for (int f = 0; f < 2; ++f) {
            int r0 = wp * 32 + f * 16 + l4 * 4;
#pragma unroll
            for (int gg = 0; gg < 8; ++gg) {
                int c = wq * 128 + gg * 16 + l15;
#pragma unroll
                for (int v = 0; v < 4; ++v)
                    pout[(size_t)(r0 + v) * 256 + c] = acc[f][gg][v];
            }
        }
    }

    __threadfence();
    grid.sync();

    // ===================== Phase 3: reduce =====================
    {
        const int gid  = bx * 512 + tid;   // 0..131071
        const int elem = gid >> 1;         // output element 0..65535
        const int half = gid & 1;          // splits [0,64) or [64,128)
        const int pt = elem >> 15;
        const int i  = elem & 32767;       // (P&127)*256 + Q
        const float* src = partial + ((size_t)(pt * 128 + half * 64)) * 32768 + i;
        float a4[4] = {};
#pragma unroll
        for (int k = 0; k < 16; ++k)
#pragma unroll
            for (int u = 0; u < 4; ++u)
                a4[u] += src[(size_t)(u * 16 + k) * 32768];
        float v = (a4[0] + a4[1]) + (a4[2] + a4[3]);
        v += __shfl_xor(v, 1, 64);         // combine the two halves
        const float scale = (0.005f - 0.00525f) * (1.0f / (float)KTOT);
        if (half == 0) out[elem] = v * scale;
    }
}

// ---------------------------------------------------------------------------
extern "C" void kernel_launch(void* const* d_in, const int* in_sizes, int n_in,
                              void* d_out, int out_size, void* d_ws, size_t ws_size,
                              hipStream_t stream)
{
    const float* pre  = (const float*)d_in[0];   // [512,100,256]
    const float* post = (const float*)d_in[1];   // [512,100,256]
    float* out = (float*)d_out;                  // [256,256]

    // ws: trace_t 33.5 MB | partial 33.5 MB
    unsigned short* trace_t = (unsigned short*)d_ws;
    float* partial = (float*)((char*)d_ws + (size_t)33554432);

    void* args[] = {(void*)&pre, (void*)&post, (void*)&trace_t,
                    (void*)&partial, (void*)&out};
    hipLaunchCooperativeKernel((const void*)stdp_mega, dim3(256), dim3(512),
                               args, 0, stream);
}

// Round 8
// 144.640 us; speedup vs baseline: 2.3636x; 2.3636x over previous
//
#include <hip/hip_runtime.h>
#include <stdint.h>

// Problem constants (from reference)
#define B_SZ   512
#define T_SZ   100
#define NPRE   256
#define NPOST  256
#define KTOT   (B_SZ * T_SZ)   // 51200

typedef __bf16 bf16x8 __attribute__((ext_vector_type(8)));
typedef float  floatx4 __attribute__((ext_vector_type(4)));

__device__ __forceinline__ uint32_t bf16_rne(float v) {
    uint32_t bits = __float_as_uint(v);
    return (bits + 0x7FFFu + ((bits >> 16) & 1u)) >> 16;
}
__device__ __forceinline__ uint32_t pack_trunc2(float a, float b) {
    return (__float_as_uint(a) >> 16) | (__float_as_uint(b) & 0xFFFF0000u);
}

// ---------------------------------------------------------------------------
// Fused scan+GEMM: 256 blocks x 512 thr; s = bx&127 (batches 4s..4s+3),
// pt = bx>>7 (p-tile). XCD pairing: bx=s and bx=s+128 read the same post
// batches on the same XCD -> second read from L2.
//
// Phase A (once): thread tid scans pre for (b = 4s + tid>>7,
// p = pt*128 + (tid&127)) — flat batched coalesced loads, fp32 carry,
// RNE->bf16, packed pairs in 50 VGPRs. No barriers.
// Phase B (per batch lb): quarter-group lb deposits its trace into A_lds
// (32 KB, fragment-line layout); all threads stage post->B_lds (64 KB,
// R6-proven); sync; 16 MFMAs; sync.
// LDS 96 KB -> 1 block/CU (proven viable in R3's counters).
// ---------------------------------------------------------------------------
__global__ __launch_bounds__(512) void stdp_fused_gemm(
    const float* __restrict__ pre, const float* __restrict__ post,
    float* __restrict__ partial)
{
    __shared__ __align__(16) unsigned short A_lds[32][512];  // 32 KB
    __shared__ __align__(16) unsigned short B_lds[64][512];  // 64 KB

    const int bx = blockIdx.x;        // 0..255
    const int s  = bx & 127;          // K-split
    const int pt = bx >> 7;           // p-tile
    const int tid = threadIdx.x;
    const int lane = tid & 63, wave = tid >> 6;
    const int wp = wave & 3, wq = wave >> 2;
    const int l15 = lane & 15, l4 = lane >> 4;

    // ---- Phase A: per-thread trace scan (batch 4s+lbo, pre-neuron p) ----
    const int p_loc = tid & 127, lbo = tid >> 7;   // lbo is wave-uniform (wave>>1)
    uint32_t pk[50];                               // bf16 pairs, t = 0..99
    {
        const int b = s * 4 + lbo;
        const float decay = 0.95122942450071400910f;  // expf(-1/20)
        const float* src = pre + (size_t)b * (T_SZ * NPRE) + pt * 128 + p_loc;
        float carry = 0.0f;
#pragma unroll
        for (int kc = 0; kc < 3; ++kc) {
            float x[32];
#pragma unroll
            for (int j = 0; j < 32; ++j)
                x[j] = src[(size_t)(kc * 32 + j) * NPRE];
#pragma unroll
            for (int j = 0; j < 16; ++j) {
                uint32_t lo = bf16_rne(carry);   // trace[t]=carry, then update
                carry = decay * (carry + x[2 * j]);
                uint32_t hi = bf16_rne(carry);
                carry = decay * (carry + x[2 * j + 1]);
                pk[kc * 16 + j] = lo | (hi << 16);
            }
        }
        float x[4];
#pragma unroll
        for (int j = 0; j < 4; ++j)
            x[j] = src[(size_t)(96 + j) * NPRE];
#pragma unroll
        for (int j = 0; j < 2; ++j) {
            uint32_t lo = bf16_rne(carry);
            carry = decay * (carry + x[2 * j]);
            uint32_t hi = bf16_rne(carry);
            carry = decay * (carry + x[2 * j + 1]);
            pk[48 + j] = lo | (hi << 16);
        }
    }

    // ---- Phase B: per-batch A-deposit + B-stage + MFMA ----
    const int q = tid & 255, hh = tid >> 8;   // B-staging role (wave-uniform hh)
    const int qg = q >> 4, q15 = q & 15;

    floatx4 acc[2][8] = {};

    for (int lb = 0; lb < 4; ++lb) {
        const int b = s * 4 + lb;

        if (lbo == lb) {
            // deposit trace into A_lds fragment lines:
            // line kc*8+pg, lane l4w*16+(p_loc&15): 16 B = k's l4w*8..+7
            const int pg = p_loc >> 4, lp = p_loc & 15;
#pragma unroll
            for (int kc = 0; kc < 3; ++kc)
#pragma unroll
                for (int l4w = 0; l4w < 4; ++l4w)
                    *(uint4*)&A_lds[kc * 8 + pg][(l4w * 16 + lp) * 8] =
                        make_uint4(pk[kc * 16 + l4w * 4], pk[kc * 16 + l4w * 4 + 1],
                                   pk[kc * 16 + l4w * 4 + 2], pk[kc * 16 + l4w * 4 + 3]);
            // kc = 3: t 96..99 real, 100..127 zero
            *(uint4*)&A_lds[24 + pg][lp * 8] = make_uint4(pk[48], pk[49], 0u, 0u);
#pragma unroll
            for (int l4w = 1; l4w < 4; ++l4w)
                *(uint4*)&A_lds[24 + pg][(l4w * 16 + lp) * 8] =
                    make_uint4(0u, 0u, 0u, 0u);
        }

        // ---- B staging: flat batched loads, no conditionals (R6-proven)
        const float* pb = post + (size_t)b * (T_SZ * NPOST) + q;
        if (hh == 0) {
            // octs 0..7 (t 0..63)
#pragma unroll
            for (int half = 0; half < 2; ++half) {
                float x[32];
#pragma unroll
                for (int j = 0; j < 32; ++j)
                    x[j] = pb[(size_t)(half * 32 + j) * NPOST];
#pragma unroll
                for (int o = 0; o < 4; ++o) {
                    int oct = half * 4 + o;
                    uint4 v = make_uint4(pack_trunc2(x[o * 8 + 0], x[o * 8 + 1]),
                                         pack_trunc2(x[o * 8 + 2], x[o * 8 + 3]),
                                         pack_trunc2(x[o * 8 + 4], x[o * 8 + 5]),
                                         pack_trunc2(x[o * 8 + 6], x[o * 8 + 7]));
                    *(uint4*)&B_lds[(oct >> 2) * 16 + qg][(((oct & 3) * 16 + q15)) * 8] = v;
                }
            }
        } else {
            // octs 8..11 (t 64..95)
            float x[32];
#pragma unroll
            for (int j = 0; j < 32; ++j)
                x[j] = pb[(size_t)(64 + j) * NPOST];
            float y[4];
#pragma unroll
            for (int j = 0; j < 4; ++j)
                y[j] = pb[(size_t)(96 + j) * NPOST];
#pragma unroll
            for (int o = 0; o < 4; ++o) {
                int oct = 8 + o;
                uint4 v = make_uint4(pack_trunc2(x[o * 8 + 0], x[o * 8 + 1]),
                                     pack_trunc2(x[o * 8 + 2], x[o * 8 + 3]),
                                     pack_trunc2(x[o * 8 + 4], x[o * 8 + 5]),
                                     pack_trunc2(x[o * 8 + 6], x[o * 8 + 7]));
                *(uint4*)&B_lds[(oct >> 2) * 16 + qg][(((oct & 3) * 16 + q15)) * 8] = v;
            }
            // oct 12: t 96..99 real, 100..103 zero
            *(uint4*)&B_lds[3 * 16 + qg][(q15) * 8] =
                make_uint4(pack_trunc2(y[0], y[1]), pack_trunc2(y[2], y[3]), 0u, 0u);
            // octs 13..15: zero
#pragma unroll
            for (int o = 13; o < 16; ++o)
                *(uint4*)&B_lds[3 * 16 + qg][(((o & 3) * 16 + q15)) * 8] =
                    make_uint4(0u, 0u, 0u, 0u);
        }
        __syncthreads();

        // ---- MFMA: 4 chunks of K=32
#pragma unroll
        for (int kc = 0; kc < 4; ++kc) {
            bf16x8 a[2], bb[8];
#pragma unroll
            for (int f = 0; f < 2; ++f)
                a[f] = *(const bf16x8*)&A_lds[kc * 8 + wp * 2 + f][lane * 8];
#pragma unroll
            for (int g = 0; g < 8; ++g)
                bb[g] = *(const bf16x8*)&B_lds[kc * 16 + wq * 8 + g][lane * 8];
#pragma unroll
            for (int f = 0; f < 2; ++f)
#pragma unroll
                for (int g = 0; g < 8; ++g)
                    acc[f][g] = __builtin_amdgcn_mfma_f32_16x16x32_bf16(
                        a[f], bb[g], acc[f][g], 0, 0, 0);
        }
        __syncthreads();
    }

    // ---- writeout: partial[bx][p_loc 128][q 256]
    // C/D layout (m89/m91): col = lane&15, row = (lane>>4)*4 + reg
    float* pout = partial + (size_t)bx * (128 * 256);
#pragma unroll
    for (int f = 0; f < 2; ++f) {
        int r0 = wp * 32 + f * 16 + l4 * 4;
#pragma unroll
        for (int g = 0; g < 8; ++g) {
            int c = wq * 128 + g * 16 + l15;
#pragma unroll
            for (int v = 0; v < 4; ++v)
                pout[(size_t)(r0 + v) * 256 + c] = acc[f][g][v];
        }
    }
}

// ---------------------------------------------------------------------------
// Reduce stage 1: partial[bx = pt*128+s][i], i = p_loc*256+q.
// 2048 blocks x 256 thr; thread t: g = t>>16 (0..7), e = t&65535,
// pt = e>>15; sums s = g*16 .. g*16+15 (4 indep chains).
// ---------------------------------------------------------------------------
__global__ __launch_bounds__(256) void stdp_reduce1(
    const float* __restrict__ partial, float* __restrict__ tmp)
{
    const int t = blockIdx.x * 256 + threadIdx.x;  // 0..524287
    const int g = t >> 16;                         // 0..7
    const int e = t & 65535;
    const int pt = e >> 15;
    const float* src = partial + ((size_t)(pt * 128 + g * 16)) * 32768 + (e & 32767);
    float a4[4] = {};
#pragma unroll
    for (int i = 0; i < 4; ++i)
#pragma unroll
        for (int u = 0; u < 4; ++u)
            a4[u] += src[(size_t)(u * 4 + i) * 32768];
    tmp[t] = (a4[0] + a4[1]) + (a4[2] + a4[3]);
}

// ---------------------------------------------------------------------------
// Reduce stage 2: 8 -> 1, scale by (A+ - A-)/(B*T).
// ---------------------------------------------------------------------------
__global__ __launch_bounds__(256) void stdp_reduce2(
    const float* __restrict__ tmp, float* __restrict__ out)
{
    const int idx = blockIdx.x * 256 + threadIdx.x;  // 0..65535
    float a[4];
#pragma unroll
    for (int u = 0; u < 4; ++u)
        a[u] = tmp[(size_t)(2 * u) * 65536 + idx] +
               tmp[(size_t)(2 * u + 1) * 65536 + idx];
    const float scale = (0.005f - 0.00525f) * (1.0f / (float)KTOT);
    out[idx] = ((a[0] + a[1]) + (a[2] + a[3])) * scale;
}

// ---------------------------------------------------------------------------
extern "C" void kernel_launch(void* const* d_in, const int* in_sizes, int n_in,
                              void* d_out, int out_size, void* d_ws, size_t ws_size,
                              hipStream_t stream)
{
    const float* pre  = (const float*)d_in[0];   // [512,100,256]
    const float* post = (const float*)d_in[1];   // [512,100,256]
    float* out = (float*)d_out;                  // [256,256]

    // ws: partial 33.5 MB | tmp 2 MB
    float* partial = (float*)d_ws;
    float* tmp     = (float*)((char*)d_ws + (size_t)33554432);

    stdp_fused_gemm<<<256, 512, 0, stream>>>(pre, post, partial);
    stdp_reduce1<<<2048, 256, 0, stream>>>(partial, tmp);
    stdp_reduce2<<<256, 256, 0, stream>>>(tmp, out);
}